// Round 10
// baseline (308.425 us; speedup 1.0000x reference)
//
#include <hip/hip_runtime.h>
#include <hip/hip_bf16.h>
#include <cstdint>

typedef __hip_bfloat16 bf16;
typedef __bf16 bf16x8 __attribute__((ext_vector_type(8)));
typedef __bf16 bf16x4 __attribute__((ext_vector_type(4)));
typedef float f32x4 __attribute__((ext_vector_type(4)));

#define LOG2E 1.4426950408889634f

__device__ __forceinline__ void gload_lds16(const void* g, void* l) {
  __builtin_amdgcn_global_load_lds(
      (const __attribute__((address_space(1))) unsigned int*)g,
      (__attribute__((address_space(3))) unsigned int*)l,
      16, 0, 0);
}

// ---- f32 -> bf16 flat convert, 8 elems/thread ----
__global__ void conv_k(const float* __restrict__ src, bf16* __restrict__ dst, int n) {
  const int i = (blockIdx.x * 256 + threadIdx.x) * 8;
  if (i >= n) return;
  const f32x4 a = *(const f32x4*)(src + i);
  const f32x4 b = *(const f32x4*)(src + i + 4);
  bf16x8 o;
#pragma unroll
  for (int j = 0; j < 4; ++j) { o[j] = (__bf16)a[j]; o[4 + j] = (__bf16)b[j]; }
  *(bf16x8*)(dst + i) = o;
}

// ---- fused 4-matrix transpose+convert: dst[z][c][r] = bf16(src[z][r][c]) ----
__global__ void transpose_conv4(
    const float* __restrict__ wq, const float* __restrict__ wk,
    const float* __restrict__ wv, const float* __restrict__ wo,
    bf16* __restrict__ dqkv, bf16* __restrict__ dout) {
  __shared__ float tile[32][33];
  const int z = blockIdx.z;
  const float* src = (z == 0) ? wq : ((z == 1) ? wk : ((z == 2) ? wv : wo));
  bf16* dst = (z < 3) ? (dqkv + (long)z * 1048576) : dout;
  const int bx = blockIdx.x * 32, by = blockIdx.y * 32;
  const int tx = threadIdx.x;
  for (int j = threadIdx.y; j < 32; j += 8)
    tile[j][tx] = src[(long)(by + j) * 1024 + bx + tx];
  __syncthreads();
  for (int j = threadIdx.y; j < 32; j += 8)
    dst[(long)(bx + j) * 1024 + by + tx] = __float2bfloat16(tile[tx][j]);
}

// ---- m97-style GEMM (128x128): C = A[M,K] * Bt[N,K]^T, bf16, scatter -> QKV ----
__global__ __launch_bounds__(256, 2) void gemm_qkv(
    const bf16* __restrict__ A, const bf16* __restrict__ Bt,
    bf16* __restrict__ Cq, bf16* __restrict__ Ck, bf16* __restrict__ Cv,
    int M, int N, int K) {
  __shared__ __align__(16) bf16 As[128 * 32];
  __shared__ __align__(16) bf16 Bs[128 * 32];

  const int tid = threadIdx.x;
  const int lane = tid & 63;
  const int wave = tid >> 6;
  const int quad = lane >> 4;
  const int l16 = lane & 15;
  const int m0 = blockIdx.y * 128;
  const int n0 = blockIdx.x * 128;
  const int wm = (wave >> 1) * 64;
  const int wn = (wave & 1) * 64;

  const f32x4 zero4 = {0.f, 0.f, 0.f, 0.f};
  f32x4 acc[4][4];
#pragma unroll
  for (int mi = 0; mi < 4; ++mi)
#pragma unroll
    for (int ni = 0; ni < 4; ++ni) acc[mi][ni] = zero4;

  const int sRow = tid >> 2;
  const int sK = (tid & 3) * 8;
  const bf16* Ag = A + (long)(m0 + sRow) * K + sK;
  const bf16* Ag2 = Ag + 64L * K;
  const bf16* Bg = Bt + (long)(n0 + sRow) * K + sK;
  const bf16* Bg2 = Bg + 64L * K;

  for (int k0 = 0; k0 < K; k0 += 32) {
    gload_lds16(Ag + k0, &As[tid * 8]);
    gload_lds16(Ag2 + k0, &As[tid * 8 + 2048]);
    gload_lds16(Bg + k0, &Bs[tid * 8]);
    gload_lds16(Bg2 + k0, &Bs[tid * 8 + 2048]);
    __syncthreads();

    bf16x8 af[4], bfv[4];
#pragma unroll
    for (int mi = 0; mi < 4; ++mi)
      af[mi] = *(const bf16x8*)&As[(wm + mi * 16 + l16) * 32 + quad * 8];
#pragma unroll
    for (int ni = 0; ni < 4; ++ni)
      bfv[ni] = *(const bf16x8*)&Bs[(wn + ni * 16 + l16) * 32 + quad * 8];
#pragma unroll
    for (int mi = 0; mi < 4; ++mi)
#pragma unroll
      for (int ni = 0; ni < 4; ++ni)
        acc[mi][ni] = __builtin_amdgcn_mfma_f32_16x16x32_bf16(af[mi], bfv[ni], acc[mi][ni], 0, 0, 0);
    __syncthreads();
  }

#pragma unroll
  for (int mi = 0; mi < 4; ++mi) {
    const int gmb = m0 + wm + mi * 16 + quad * 4;
#pragma unroll
    for (int ni = 0; ni < 4; ++ni) {
      const int n = n0 + wn + ni * 16 + l16;
      const int which = n >> 10, rem = n & 1023;
      const int h = rem >> 6, hd = rem & 63;
      bf16* dst = (which == 0) ? Cq : ((which == 1) ? Ck : Cv);
#pragma unroll
      for (int r = 0; r < 4; ++r) {
        const int gm = gmb + r;
        const int b = gm >> 11, t = gm & 2047;
        dst[(((long)(b * 16 + h)) * 2048 + t) * 64 + hd] = __float2bfloat16(acc[mi][ni][r]);
      }
    }
  }
}

// ---- output GEMM 64x128 tile (512 blocks): ctx(bf16) @ WtO^T + bias -> f32 ----
__global__ __launch_bounds__(256, 4) void gemm_out(
    const bf16* __restrict__ A, const bf16* __restrict__ Bt,
    const float* __restrict__ bias, float* __restrict__ Cout,
    int M, int N, int K) {
  __shared__ __align__(16) bf16 As[64 * 32];
  __shared__ __align__(16) bf16 Bs[128 * 32];

  const int tid = threadIdx.x;
  const int lane = tid & 63;
  const int wave = tid >> 6;
  const int quad = lane >> 4;
  const int l16 = lane & 15;
  const int m0 = blockIdx.y * 64;
  const int n0 = blockIdx.x * 128;
  const int wm = (wave & 1) * 32;
  const int wn = (wave >> 1) * 64;

  const f32x4 zero4 = {0.f, 0.f, 0.f, 0.f};
  f32x4 acc[2][4];
#pragma unroll
  for (int mi = 0; mi < 2; ++mi)
#pragma unroll
    for (int ni = 0; ni < 4; ++ni) acc[mi][ni] = zero4;

  const int sRow = tid >> 2;
  const int sK = (tid & 3) * 8;
  const bf16* Ag = A + (long)(m0 + sRow) * K + sK;
  const bf16* Bg = Bt + (long)(n0 + sRow) * K + sK;
  const bf16* Bg2 = Bg + 64L * K;

  for (int k0 = 0; k0 < K; k0 += 32) {
    gload_lds16(Ag + k0, &As[tid * 8]);
    gload_lds16(Bg + k0, &Bs[tid * 8]);
    gload_lds16(Bg2 + k0, &Bs[tid * 8 + 2048]);
    __syncthreads();

    bf16x8 af[2], bfv[4];
#pragma unroll
    for (int mi = 0; mi < 2; ++mi)
      af[mi] = *(const bf16x8*)&As[(wm + mi * 16 + l16) * 32 + quad * 8];
#pragma unroll
    for (int ni = 0; ni < 4; ++ni)
      bfv[ni] = *(const bf16x8*)&Bs[(wn + ni * 16 + l16) * 32 + quad * 8];
#pragma unroll
    for (int mi = 0; mi < 2; ++mi)
#pragma unroll
      for (int ni = 0; ni < 4; ++ni)
        acc[mi][ni] = __builtin_amdgcn_mfma_f32_16x16x32_bf16(af[mi], bfv[ni], acc[mi][ni], 0, 0, 0);
    __syncthreads();
  }

#pragma unroll
  for (int mi = 0; mi < 2; ++mi) {
    const int gmb = m0 + wm + mi * 16 + quad * 4;
#pragma unroll
    for (int ni = 0; ni < 4; ++ni) {
      const int n = n0 + wn + ni * 16 + l16;
      const float bv = bias[n];
#pragma unroll
      for (int r = 0; r < 4; ++r)
        Cout[(long)(gmb + r) * N + n] = acc[mi][ni][r] + bv;
    }
  }
}

// ---- flash attention v4: Q-tile 128 (2 halves/wave), K-tile 128, LPT ----
// grid (16, 32); block 256 (4 waves x 32 q-rows)
__global__ __launch_bounds__(256, 3) void attn_kernel(
    const bf16* __restrict__ Q, const bf16* __restrict__ Kg, const bf16* __restrict__ Vg,
    bf16* __restrict__ ctx) {
  constexpr int KSTR = 72, VSTR = 136, PSTR = 136;
  __shared__ __align__(16) bf16 Ks[128 * KSTR];     // [t][d]
  __shared__ __align__(16) bf16 Vt[64 * VSTR];      // [d][t]
  __shared__ __align__(16) bf16 Ps[4 * 16 * PSTR];  // per-wave [q16][k]

  const int tid = threadIdx.x;
  const int lane = tid & 63;
  const int wave = tid >> 6;
  const int quad = lane >> 4;
  const int l16 = lane & 15;
  const int qt = 15 - (int)blockIdx.x;   // LPT
  const int bh = blockIdx.y;
  const long base = (long)bh * 2048 * 64;
  const int qb0 = qt * 128 + wave * 32;  // wave's 32 q-rows

  bf16x8 qf[2][2];
#pragma unroll
  for (int ph = 0; ph < 2; ++ph) {
    const bf16* qp = Q + base + (long)(qb0 + ph * 16 + l16) * 64;
    qf[ph][0] = *(const bf16x8*)(qp + quad * 8);
    qf[ph][1] = *(const bf16x8*)(qp + 32 + quad * 8);
  }

  const f32x4 zero4 = {0.f, 0.f, 0.f, 0.f};
  float m_i[2] = {-1e30f, -1e30f}, l_i[2] = {0.f, 0.f};
  f32x4 oacc[2][4];
#pragma unroll
  for (int ph = 0; ph < 2; ++ph)
#pragma unroll
    for (int nb = 0; nb < 4; ++nb) oacc[ph][nb] = zero4;

  const int krow = tid >> 1;
  const int kc32 = (tid & 1) * 32;
  const int vr4 = (tid & 31) * 4;
  const int vd8 = (tid >> 5) * 8;

  const int nk = qt + 1;
  bf16x8 kr[4], vv[4];
  {
    const bf16* kp = Kg + base + (long)krow * 64 + kc32;
#pragma unroll
    for (int i = 0; i < 4; ++i) kr[i] = *(const bf16x8*)(kp + i * 8);
#pragma unroll
    for (int i = 0; i < 4; ++i)
      vv[i] = *(const bf16x8*)(Vg + base + (long)(vr4 + i) * 64 + vd8);
  }

  for (int kt = 0; kt < nk; ++kt) {
    const int k0 = kt * 128;
#pragma unroll
    for (int i = 0; i < 4; ++i)
      *(bf16x8*)&Ks[krow * KSTR + kc32 + i * 8] = kr[i];
#pragma unroll
    for (int j = 0; j < 8; ++j) {
      bf16x4 t;
      t[0] = vv[0][j]; t[1] = vv[1][j]; t[2] = vv[2][j]; t[3] = vv[3][j];
      *(bf16x4*)&Vt[(vd8 + j) * VSTR + vr4] = t;
    }
    __syncthreads();
    if (kt + 1 < nk) {
      const bf16* kp = Kg + base + (long)(k0 + 128 + krow) * 64 + kc32;
#pragma unroll
      for (int i = 0; i < 4; ++i) kr[i] = *(const bf16x8*)(kp + i * 8);
#pragma unroll
      for (int i = 0; i < 4; ++i)
        vv[i] = *(const bf16x8*)(Vg + base + (long)(k0 + 128 + vr4 + i) * 64 + vd8);
    }

#pragma unroll
    for (int ph = 0; ph < 2; ++ph) {
      const int q = qb0 + ph * 16 + l16;

      // S^T = mfma(K-frag, Q-frag): lane holds S^T[k0+kb*16+quad*4+r][q=l16]
      f32x4 s[8];
#pragma unroll
      for (int kb = 0; kb < 8; ++kb) {
        const bf16x8 kb0 = *(const bf16x8*)&Ks[(kb * 16 + l16) * KSTR + quad * 8];
        const bf16x8 kb1 = *(const bf16x8*)&Ks[(kb * 16 + l16) * KSTR + 32 + quad * 8];
        f32x4 a = zero4;
        a = __builtin_amdgcn_mfma_f32_16x16x32_bf16(kb0, qf[ph][0], a, 0, 0, 0);
        a = __builtin_amdgcn_mfma_f32_16x16x32_bf16(kb1, qf[ph][1], a, 0, 0, 0);
        s[kb] = a;
      }

      float mloc = -1e30f;
#pragma unroll
      for (int kb = 0; kb < 8; ++kb) {
#pragma unroll
        for (int r = 0; r < 4; ++r) {
          const int kidx = k0 + kb * 16 + quad * 4 + r;
          float sv = s[kb][r] * 0.125f;
          sv = (kidx <= q) ? sv : -1e30f;
          s[kb][r] = sv;
          mloc = fmaxf(mloc, sv);
        }
      }
      mloc = fmaxf(mloc, __shfl_xor(mloc, 16));
      mloc = fmaxf(mloc, __shfl_xor(mloc, 32));

      const float mn = fmaxf(m_i[ph], mloc);
      const float alpha = exp2f((m_i[ph] - mn) * LOG2E);
      float rsum = 0.f;
#pragma unroll
      for (int kb = 0; kb < 8; ++kb) {
        bf16x4 pk;
#pragma unroll
        for (int r = 0; r < 4; ++r) {
          const float p = exp2f((s[kb][r] - mn) * LOG2E);
          rsum += p;
          pk[r] = (__bf16)p;
        }
        *(bf16x4*)&Ps[wave * (16 * PSTR) + l16 * PSTR + kb * 16 + quad * 4] = pk;
      }
      rsum += __shfl_xor(rsum, 16);
      rsum += __shfl_xor(rsum, 32);
      l_i[ph] = l_i[ph] * alpha + rsum;
      m_i[ph] = mn;

      float alr[4];
#pragma unroll
      for (int r = 0; r < 4; ++r) alr[r] = __shfl(alpha, quad * 4 + r);
#pragma unroll
      for (int nb = 0; nb < 4; ++nb)
#pragma unroll
        for (int r = 0; r < 4; ++r) oacc[ph][nb][r] *= alr[r];

      __asm__ volatile("s_waitcnt lgkmcnt(0)" ::: "memory");

      bf16x8 pa[4];
#pragma unroll
      for (int kk = 0; kk < 4; ++kk)
        pa[kk] = *(const bf16x8*)&Ps[wave * (16 * PSTR) + l16 * PSTR + kk * 32 + quad * 8];
#pragma unroll
      for (int nb2 = 0; nb2 < 4; ++nb2) {
#pragma unroll
        for (int kk = 0; kk < 4; ++kk) {
          const bf16x8 vb = *(const bf16x8*)&Vt[(nb2 * 16 + l16) * VSTR + kk * 32 + quad * 8];
          oacc[ph][nb2] = __builtin_amdgcn_mfma_f32_16x16x32_bf16(pa[kk], vb, oacc[ph][nb2], 0, 0, 0);
        }
      }
    }
    __syncthreads();
  }

  // epilogue: ctx[b, t, head*64+d]
  const int b = bh >> 4, head = bh & 15;
#pragma unroll
  for (int ph = 0; ph < 2; ++ph) {
    float linv[4];
#pragma unroll
    for (int r = 0; r < 4; ++r) linv[r] = 1.0f / __shfl(l_i[ph], quad * 4 + r);
#pragma unroll
    for (int r = 0; r < 4; ++r) {
      const int t = qb0 + ph * 16 + quad * 4 + r;
#pragma unroll
      for (int nb2 = 0; nb2 < 4; ++nb2) {
        const int d = head * 64 + nb2 * 16 + l16;
        ctx[((long)b * 2048 + t) * 1024 + d] = __float2bfloat16(oacc[ph][nb2][r] * linv[r]);
      }
    }
  }
}

extern "C" void kernel_launch(void* const* d_in, const int* in_sizes, int n_in,
                              void* d_out, int out_size, void* d_ws, size_t ws_size,
                              hipStream_t stream) {
  const float* x  = (const float*)d_in[0];
  const float* wq = (const float*)d_in[1];
  const float* wk = (const float*)d_in[2];
  const float* wv = (const float*)d_in[3];
  const float* wo = (const float*)d_in[4];
  const float* bo = (const float*)d_in[5];
  float* out = (float*)d_out;

  bf16* Wtqkv = (bf16*)d_ws;            // 3 * 1048576
  bf16* Wto   = Wtqkv + 3145728;        // 1048576
  bf16* xb    = Wto + 1048576;          // 4194304 (reused as Cx)
  bf16* Qb    = xb + 4194304;
  bf16* Kb    = Qb + 4194304;
  bf16* Vb    = Kb + 4194304;
  bf16* Cx    = xb;

  hipLaunchKernelGGL(conv_k, dim3(2048), dim3(256), 0, stream, x, xb, 4194304);
  hipLaunchKernelGGL(transpose_conv4, dim3(32, 32, 4), dim3(32, 8), 0, stream,
                     wq, wk, wv, wo, Wtqkv, Wto);

  hipLaunchKernelGGL(gemm_qkv, dim3(24, 32), dim3(256), 0, stream,
                     xb, Wtqkv, Qb, Kb, Vb, 4096, 3072, 1024);

  hipLaunchKernelGGL(attn_kernel, dim3(16, 32), dim3(256), 0, stream, Qb, Kb, Vb, Cx);

  hipLaunchKernelGGL(gemm_out, dim3(8, 64), dim3(256), 0, stream,
                     Cx, Wto, bo, out, 4096, 1024, 1024);
}

// Round 11
// 227.085 us; speedup vs baseline: 1.3582x; 1.3582x over previous
//
#include <hip/hip_runtime.h>
#include <hip/hip_bf16.h>
#include <cstdint>

typedef __hip_bfloat16 bf16;
typedef __bf16 bf16x8 __attribute__((ext_vector_type(8)));
typedef __bf16 bf16x4 __attribute__((ext_vector_type(4)));
typedef float f32x4 __attribute__((ext_vector_type(4)));

#define LOG2E 1.4426950408889634f

__device__ __forceinline__ void gload_lds16(const void* g, void* l) {
  __builtin_amdgcn_global_load_lds(
      (const __attribute__((address_space(1))) unsigned int*)g,
      (__attribute__((address_space(3))) unsigned int*)l,
      16, 0, 0);
}

// ---- f32 -> bf16 flat convert, 8 elems/thread ----
__global__ void conv_k(const float* __restrict__ src, bf16* __restrict__ dst, int n) {
  const int i = (blockIdx.x * 256 + threadIdx.x) * 8;
  if (i >= n) return;
  const f32x4 a = *(const f32x4*)(src + i);
  const f32x4 b = *(const f32x4*)(src + i + 4);
  bf16x8 o;
#pragma unroll
  for (int j = 0; j < 4; ++j) { o[j] = (__bf16)a[j]; o[4 + j] = (__bf16)b[j]; }
  *(bf16x8*)(dst + i) = o;
}

// ---- fused 4-matrix transpose+convert: dst[z][c][r] = bf16(src[z][r][c]) ----
__global__ void transpose_conv4(
    const float* __restrict__ wq, const float* __restrict__ wk,
    const float* __restrict__ wv, const float* __restrict__ wo,
    bf16* __restrict__ dqkv, bf16* __restrict__ dout) {
  __shared__ float tile[32][33];
  const int z = blockIdx.z;
  const float* src = (z == 0) ? wq : ((z == 1) ? wk : ((z == 2) ? wv : wo));
  bf16* dst = (z < 3) ? (dqkv + (long)z * 1048576) : dout;
  const int bx = blockIdx.x * 32, by = blockIdx.y * 32;
  const int tx = threadIdx.x;
  for (int j = threadIdx.y; j < 32; j += 8)
    tile[j][tx] = src[(long)(by + j) * 1024 + bx + tx];
  __syncthreads();
  for (int j = threadIdx.y; j < 32; j += 8)
    dst[(long)(bx + j) * 1024 + by + tx] = __float2bfloat16(tile[tx][j]);
}

// ---- m97-style GEMM (128x128): C = A[M,K] * Bt[N,K]^T, bf16, scatter -> QKV ----
__global__ __launch_bounds__(256, 2) void gemm_qkv(
    const bf16* __restrict__ A, const bf16* __restrict__ Bt,
    bf16* __restrict__ Cq, bf16* __restrict__ Ck, bf16* __restrict__ Cv,
    int M, int N, int K) {
  __shared__ __align__(16) bf16 As[128 * 32];
  __shared__ __align__(16) bf16 Bs[128 * 32];

  const int tid = threadIdx.x;
  const int lane = tid & 63;
  const int wave = tid >> 6;
  const int quad = lane >> 4;
  const int l16 = lane & 15;
  const int m0 = blockIdx.y * 128;
  const int n0 = blockIdx.x * 128;
  const int wm = (wave >> 1) * 64;
  const int wn = (wave & 1) * 64;

  const f32x4 zero4 = {0.f, 0.f, 0.f, 0.f};
  f32x4 acc[4][4];
#pragma unroll
  for (int mi = 0; mi < 4; ++mi)
#pragma unroll
    for (int ni = 0; ni < 4; ++ni) acc[mi][ni] = zero4;

  const int sRow = tid >> 2;
  const int sK = (tid & 3) * 8;
  const bf16* Ag = A + (long)(m0 + sRow) * K + sK;
  const bf16* Ag2 = Ag + 64L * K;
  const bf16* Bg = Bt + (long)(n0 + sRow) * K + sK;
  const bf16* Bg2 = Bg + 64L * K;

  for (int k0 = 0; k0 < K; k0 += 32) {
    gload_lds16(Ag + k0, &As[tid * 8]);
    gload_lds16(Ag2 + k0, &As[tid * 8 + 2048]);
    gload_lds16(Bg + k0, &Bs[tid * 8]);
    gload_lds16(Bg2 + k0, &Bs[tid * 8 + 2048]);
    __syncthreads();

    bf16x8 af[4], bfv[4];
#pragma unroll
    for (int mi = 0; mi < 4; ++mi)
      af[mi] = *(const bf16x8*)&As[(wm + mi * 16 + l16) * 32 + quad * 8];
#pragma unroll
    for (int ni = 0; ni < 4; ++ni)
      bfv[ni] = *(const bf16x8*)&Bs[(wn + ni * 16 + l16) * 32 + quad * 8];
#pragma unroll
    for (int mi = 0; mi < 4; ++mi)
#pragma unroll
      for (int ni = 0; ni < 4; ++ni)
        acc[mi][ni] = __builtin_amdgcn_mfma_f32_16x16x32_bf16(af[mi], bfv[ni], acc[mi][ni], 0, 0, 0);
    __syncthreads();
  }

#pragma unroll
  for (int mi = 0; mi < 4; ++mi) {
    const int gmb = m0 + wm + mi * 16 + quad * 4;
#pragma unroll
    for (int ni = 0; ni < 4; ++ni) {
      const int n = n0 + wn + ni * 16 + l16;
      const int which = n >> 10, rem = n & 1023;
      const int h = rem >> 6, hd = rem & 63;
      bf16* dst = (which == 0) ? Cq : ((which == 1) ? Ck : Cv);
#pragma unroll
      for (int r = 0; r < 4; ++r) {
        const int gm = gmb + r;
        const int b = gm >> 11, t = gm & 2047;
        dst[(((long)(b * 16 + h)) * 2048 + t) * 64 + hd] = __float2bfloat16(acc[mi][ni][r]);
      }
    }
  }
}

// ---- output GEMM 64x128 tile (512 blocks): ctx(bf16) @ WtO^T + bias -> f32 ----
__global__ __launch_bounds__(256, 4) void gemm_out(
    const bf16* __restrict__ A, const bf16* __restrict__ Bt,
    const float* __restrict__ bias, float* __restrict__ Cout,
    int M, int N, int K) {
  __shared__ __align__(16) bf16 As[64 * 32];
  __shared__ __align__(16) bf16 Bs[128 * 32];

  const int tid = threadIdx.x;
  const int lane = tid & 63;
  const int wave = tid >> 6;
  const int quad = lane >> 4;
  const int l16 = lane & 15;
  const int m0 = blockIdx.y * 64;
  const int n0 = blockIdx.x * 128;
  const int wm = (wave & 1) * 32;
  const int wn = (wave >> 1) * 64;

  const f32x4 zero4 = {0.f, 0.f, 0.f, 0.f};
  f32x4 acc[2][4];
#pragma unroll
  for (int mi = 0; mi < 2; ++mi)
#pragma unroll
    for (int ni = 0; ni < 4; ++ni) acc[mi][ni] = zero4;

  const int sRow = tid >> 2;
  const int sK = (tid & 3) * 8;
  const bf16* Ag = A + (long)(m0 + sRow) * K + sK;
  const bf16* Bg = Bt + (long)(n0 + sRow) * K + sK;
  const bf16* Bg2 = Bg + 64L * K;

  for (int k0 = 0; k0 < K; k0 += 32) {
    gload_lds16(Ag + k0, &As[tid * 8]);
    gload_lds16(Bg + k0, &Bs[tid * 8]);
    gload_lds16(Bg2 + k0, &Bs[tid * 8 + 2048]);
    __syncthreads();

    bf16x8 af[2], bfv[4];
#pragma unroll
    for (int mi = 0; mi < 2; ++mi)
      af[mi] = *(const bf16x8*)&As[(wm + mi * 16 + l16) * 32 + quad * 8];
#pragma unroll
    for (int ni = 0; ni < 4; ++ni)
      bfv[ni] = *(const bf16x8*)&Bs[(wn + ni * 16 + l16) * 32 + quad * 8];
#pragma unroll
    for (int mi = 0; mi < 2; ++mi)
#pragma unroll
      for (int ni = 0; ni < 4; ++ni)
        acc[mi][ni] = __builtin_amdgcn_mfma_f32_16x16x32_bf16(af[mi], bfv[ni], acc[mi][ni], 0, 0, 0);
    __syncthreads();
  }

#pragma unroll
  for (int mi = 0; mi < 2; ++mi) {
    const int gmb = m0 + wm + mi * 16 + quad * 4;
#pragma unroll
    for (int ni = 0; ni < 4; ++ni) {
      const int n = n0 + wn + ni * 16 + l16;
      const float bv = bias[n];
#pragma unroll
      for (int r = 0; r < 4; ++r)
        Cout[(long)(gmb + r) * N + n] = acc[mi][ni][r] + bv;
    }
  }
}

// ---- flash attention v3 (R9-proven): S^T trick, Q-tile 64, K-tile 128, LPT ----
// grid (32, 32); block 256 (4 waves x 16 q-rows)
__global__ __launch_bounds__(256, 3) void attn_kernel(
    const bf16* __restrict__ Q, const bf16* __restrict__ Kg, const bf16* __restrict__ Vg,
    bf16* __restrict__ ctx) {
  constexpr int KSTR = 72, VSTR = 136, PSTR = 136;
  __shared__ __align__(16) bf16 Ks[128 * KSTR];     // [t][d]
  __shared__ __align__(16) bf16 Vt[64 * VSTR];      // [d][t]
  __shared__ __align__(16) bf16 Ps[4 * 16 * PSTR];  // per-wave [q][k]

  const int tid = threadIdx.x;
  const int lane = tid & 63;
  const int wave = tid >> 6;
  const int quad = lane >> 4;
  const int l16 = lane & 15;
  const int qt = (int)gridDim.x - 1 - (int)blockIdx.x;
  const int bh = blockIdx.y;
  const long base = (long)bh * 2048 * 64;
  const int qbase = qt * 64 + wave * 16;
  const int q = qbase + l16;  // this lane's softmax row

  const bf16x8 qf0 = *(const bf16x8*)(Q + base + (long)(qbase + l16) * 64 + quad * 8);
  const bf16x8 qf1 = *(const bf16x8*)(Q + base + (long)(qbase + l16) * 64 + 32 + quad * 8);

  const f32x4 zero4 = {0.f, 0.f, 0.f, 0.f};
  float m_i = -1e30f, l_i = 0.f;
  f32x4 oacc[4];
#pragma unroll
  for (int nb = 0; nb < 4; ++nb) oacc[nb] = zero4;

  const int krow = tid >> 1;
  const int kc32 = (tid & 1) * 32;
  const int vr4 = (tid & 31) * 4;
  const int vd8 = (tid >> 5) * 8;

  const int nk = (qt + 2) >> 1;
  bf16x8 kr[4], vv[4];
  {
    const bf16* kp = Kg + base + (long)krow * 64 + kc32;
#pragma unroll
    for (int i = 0; i < 4; ++i) kr[i] = *(const bf16x8*)(kp + i * 8);
#pragma unroll
    for (int i = 0; i < 4; ++i)
      vv[i] = *(const bf16x8*)(Vg + base + (long)(vr4 + i) * 64 + vd8);
  }

  for (int kt = 0; kt < nk; ++kt) {
    const int k0 = kt * 128;
#pragma unroll
    for (int i = 0; i < 4; ++i)
      *(bf16x8*)&Ks[krow * KSTR + kc32 + i * 8] = kr[i];
#pragma unroll
    for (int j = 0; j < 8; ++j) {
      bf16x4 t;
      t[0] = vv[0][j]; t[1] = vv[1][j]; t[2] = vv[2][j]; t[3] = vv[3][j];
      *(bf16x4*)&Vt[(vd8 + j) * VSTR + vr4] = t;
    }
    __syncthreads();
    if (kt + 1 < nk) {
      const bf16* kp = Kg + base + (long)(k0 + 128 + krow) * 64 + kc32;
#pragma unroll
      for (int i = 0; i < 4; ++i) kr[i] = *(const bf16x8*)(kp + i * 8);
#pragma unroll
      for (int i = 0; i < 4; ++i)
        vv[i] = *(const bf16x8*)(Vg + base + (long)(k0 + 128 + vr4 + i) * 64 + vd8);
    }

    // S^T = mfma(K-frag, Q-frag): lane holds S^T[k=k0+kb*16+quad*4+r][q=l16]
    f32x4 s[8];
#pragma unroll
    for (int kb = 0; kb < 8; ++kb) {
      const bf16x8 kb0 = *(const bf16x8*)&Ks[(kb * 16 + l16) * KSTR + quad * 8];
      const bf16x8 kb1 = *(const bf16x8*)&Ks[(kb * 16 + l16) * KSTR + 32 + quad * 8];
      f32x4 a = zero4;
      a = __builtin_amdgcn_mfma_f32_16x16x32_bf16(kb0, qf0, a, 0, 0, 0);
      a = __builtin_amdgcn_mfma_f32_16x16x32_bf16(kb1, qf1, a, 0, 0, 0);
      s[kb] = a;
    }

    // scale + causal + per-lane max over 32 elems, then cross-quad reduce
    float mloc = -1e30f;
#pragma unroll
    for (int kb = 0; kb < 8; ++kb) {
#pragma unroll
      for (int r = 0; r < 4; ++r) {
        const int kidx = k0 + kb * 16 + quad * 4 + r;
        float sv = s[kb][r] * 0.125f;
        sv = (kidx <= q) ? sv : -1e30f;
        s[kb][r] = sv;
        mloc = fmaxf(mloc, sv);
      }
    }
    mloc = fmaxf(mloc, __shfl_xor(mloc, 16));
    mloc = fmaxf(mloc, __shfl_xor(mloc, 32));

    const float mn = fmaxf(m_i, mloc);
    const float alpha = exp2f((m_i - mn) * LOG2E);
    float rsum = 0.f;
#pragma unroll
    for (int kb = 0; kb < 8; ++kb) {
      bf16x4 pk;
#pragma unroll
      for (int r = 0; r < 4; ++r) {
        const float p = exp2f((s[kb][r] - mn) * LOG2E);
        rsum += p;
        pk[r] = (__bf16)p;
      }
      *(bf16x4*)&Ps[wave * (16 * PSTR) + l16 * PSTR + kb * 16 + quad * 4] = pk;
    }
    rsum += __shfl_xor(rsum, 16);
    rsum += __shfl_xor(rsum, 32);
    l_i = l_i * alpha + rsum;
    m_i = mn;

    // broadcast alpha to O C-layout rows (q = quad*4+r)
    float alr[4];
#pragma unroll
    for (int r = 0; r < 4; ++r) alr[r] = __shfl(alpha, quad * 4 + r);
#pragma unroll
    for (int nb = 0; nb < 4; ++nb)
#pragma unroll
      for (int r = 0; r < 4; ++r) oacc[nb][r] *= alr[r];

    __asm__ volatile("s_waitcnt lgkmcnt(0)" ::: "memory");

    // O += P V
    bf16x8 pa[4];
#pragma unroll
    for (int kk = 0; kk < 4; ++kk)
      pa[kk] = *(const bf16x8*)&Ps[wave * (16 * PSTR) + l16 * PSTR + kk * 32 + quad * 8];
#pragma unroll
    for (int nb2 = 0; nb2 < 4; ++nb2) {
#pragma unroll
      for (int kk = 0; kk < 4; ++kk) {
        const bf16x8 vb = *(const bf16x8*)&Vt[(nb2 * 16 + l16) * VSTR + kk * 32 + quad * 8];
        oacc[nb2] = __builtin_amdgcn_mfma_f32_16x16x32_bf16(pa[kk], vb, oacc[nb2], 0, 0, 0);
      }
    }
    __syncthreads();
  }

  // epilogue
  const int b = bh >> 4, h = bh & 15;
  float linv[4];
#pragma unroll
  for (int r = 0; r < 4; ++r) linv[r] = 1.0f / __shfl(l_i, quad * 4 + r);
#pragma unroll
  for (int r = 0; r < 4; ++r) {
    const int t = qbase + quad * 4 + r;
#pragma unroll
    for (int nb2 = 0; nb2 < 4; ++nb2) {
      const int d = h * 64 + nb2 * 16 + l16;
      ctx[((long)b * 2048 + t) * 1024 + d] = __float2bfloat16(oacc[nb2][r] * linv[r]);
    }
  }
}

extern "C" void kernel_launch(void* const* d_in, const int* in_sizes, int n_in,
                              void* d_out, int out_size, void* d_ws, size_t ws_size,
                              hipStream_t stream) {
  const float* x  = (const float*)d_in[0];
  const float* wq = (const float*)d_in[1];
  const float* wk = (const float*)d_in[2];
  const float* wv = (const float*)d_in[3];
  const float* wo = (const float*)d_in[4];
  const float* bo = (const float*)d_in[5];
  float* out = (float*)d_out;

  bf16* Wtqkv = (bf16*)d_ws;            // 3 * 1048576
  bf16* Wto   = Wtqkv + 3145728;        // 1048576
  bf16* xb    = Wto + 1048576;          // 4194304 (reused as Cx)
  bf16* Qb    = xb + 4194304;
  bf16* Kb    = Qb + 4194304;
  bf16* Vb    = Kb + 4194304;
  bf16* Cx    = xb;

  hipLaunchKernelGGL(conv_k, dim3(2048), dim3(256), 0, stream, x, xb, 4194304);
  hipLaunchKernelGGL(transpose_conv4, dim3(32, 32, 4), dim3(32, 8), 0, stream,
                     wq, wk, wv, wo, Wtqkv, Wto);

  hipLaunchKernelGGL(gemm_qkv, dim3(24, 32), dim3(256), 0, stream,
                     xb, Wtqkv, Qb, Kb, Vb, 4096, 3072, 1024);

  hipLaunchKernelGGL(attn_kernel, dim3(32, 32), dim3(256), 0, stream, Qb, Kb, Vb, Cx);

  hipLaunchKernelGGL(gemm_out, dim3(8, 64), dim3(256), 0, stream,
                     Cx, Wto, bo, out, 4096, 1024, 1024);
}